// Round 2
// baseline (779.743 us; speedup 1.0000x reference)
//
#include <hip/hip_runtime.h>

typedef unsigned short u16;
typedef unsigned int u32;
typedef __attribute__((ext_vector_type(8))) short short8;
typedef __attribute__((ext_vector_type(4))) float f32x4;
typedef __attribute__((ext_vector_type(2))) unsigned int u32x2;

#define TT 300
#define VT 7500                      // 25*300 flattened (v,t) columns
#define C_IN 256
#define C_OUT 256

__device__ __forceinline__ u16 f2bf(float f) {
  u32 u = __float_as_uint(f);
  return (u16)((u + 0x7fffu + ((u >> 16) & 1u)) >> 16);  // RNE, finite inputs
}

// ---------------- K0: W fp32 -> bf16 (128 KB in ws) ----------------
__global__ void k0_wcast(const float* __restrict__ W, u16* __restrict__ Wb) {
  int i = (blockIdx.x * 256 + threadIdx.x) * 4;
  f32x4 w = *(const f32x4*)(W + i);
  u32x2 pk;
  pk[0] = (u32)f2bf(w[0]) | ((u32)f2bf(w[1]) << 16);
  pk[1] = (u32)f2bf(w[2]) | ((u32)f2bf(w[3]) << 16);
  *(u32x2*)(Wb + i) = pk;
}

// ---------------- fused: stencil + GEMM + bias, no LDS, no barriers ----------
// grid (59 gblk, 32 n), 512 thr = 8 waves: gw = wv&3 (32 g each), ow = wv>>2 (128 o each)
// B-frag built in registers: lane l holds agg[g = base+(l&15)][c = ks*32+quad*8+j]
__global__ __launch_bounds__(512) void k_fused(
    const float* __restrict__ x, const float* __restrict__ A,
    const u16* __restrict__ Wb, const float* __restrict__ bias,
    float* __restrict__ out) {
  const int tid = threadIdx.x;
  const int l = tid & 63, wv = tid >> 6;
  const int gw = wv & 3, ow = wv >> 2;
  const int quad = l >> 4, m16 = l & 15;
  const int cb = blockIdx.x, n = blockIdx.y;

  const float* xn = x + (size_t)n * C_IN * VT;

  // per-lane stencil setup for the wave's two 16-g tiles
  int gcol[2];
  float ac[2][3];
  const float* xb[2][3];
#pragma unroll
  for (int gt = 0; gt < 2; ++gt) {
    int g = cb * 128 + gw * 32 + gt * 16 + m16;
    gcol[gt] = g;
    int gc = (g < VT) ? g : (VT - 1);          // clamp for loads; store masked
    int w = gc / TT, t = gc - w * TT;
    ac[gt][0] = (w > 0) ? A[(w - 1) * 25 + w] : 0.0f;
    ac[gt][1] = A[w * 25 + w];
    ac[gt][2] = (w < 24) ? A[(w + 1) * 25 + w] : 0.0f;
    int wm = (w > 0) ? w - 1 : 0, wp = (w < 24) ? w + 1 : 24;
    const float* base = xn + (size_t)(quad * 8) * VT + t;   // c-window start
    xb[gt][0] = base + wm * TT;
    xb[gt][1] = base + w * TT;
    xb[gt][2] = base + wp * TT;
  }

  const u16* wrow = Wb + (size_t)(ow * 128 + m16) * C_IN + quad * 8;

  f32x4 acc[8][2] = {};                        // [o-tile][g-tile]
  for (int ks = 0; ks < 8; ++ks) {             // k = c in 32-chunks
    // build B-fragments from x via 3-tap stencil (fp32 -> bf16)
    short8 bf[2];
#pragma unroll
    for (int gt = 0; gt < 2; ++gt) {
#pragma unroll
      for (int j = 0; j < 8; ++j) {
        size_t off = (size_t)(ks * 32 + j) * VT;
        float xm = xb[gt][0][off];
        float x0 = xb[gt][1][off];
        float xp = xb[gt][2][off];
        float r = ac[gt][0] * xm + ac[gt][1] * x0 + ac[gt][2] * xp;
        bf[gt][j] = (short)f2bf(r);
      }
    }
    // A-fragments straight from global (W bf16 is L1/L2-hot, 16B/lane)
    short8 af[8];
#pragma unroll
    for (int ot = 0; ot < 8; ++ot)
      af[ot] = *(const short8*)(wrow + (size_t)(ot * 16) * C_IN + ks * 32);
#pragma unroll
    for (int ot = 0; ot < 8; ++ot)
#pragma unroll
      for (int gt = 0; gt < 2; ++gt)
        acc[ot][gt] = __builtin_amdgcn_mfma_f32_16x16x32_bf16(af[ot], bf[gt], acc[ot][gt], 0, 0, 0);
  }

  // epilogue: C layout col=lane&15 (= g), row=quad*4+reg (= o within 16)
  float* outn = out + (size_t)n * C_OUT * VT;
#pragma unroll
  for (int ot = 0; ot < 8; ++ot) {
    int o0 = ow * 128 + ot * 16 + quad * 4;
    f32x4 bv = *(const f32x4*)(bias + o0);
#pragma unroll
    for (int gt = 0; gt < 2; ++gt) {
      int col = gcol[gt];
      if (col < VT) {
        float* p = outn + (size_t)o0 * VT + col;
        __builtin_nontemporal_store(acc[ot][gt][0] + bv[0], p);
        __builtin_nontemporal_store(acc[ot][gt][1] + bv[1], p + VT);
        __builtin_nontemporal_store(acc[ot][gt][2] + bv[2], p + 2 * VT);
        __builtin_nontemporal_store(acc[ot][gt][3] + bv[3], p + 3 * VT);
      }
    }
  }
}

extern "C" void kernel_launch(void* const* d_in, const int* in_sizes, int n_in,
                              void* d_out, int out_size, void* d_ws, size_t ws_size,
                              hipStream_t stream) {
  (void)in_sizes; (void)n_in; (void)out_size; (void)ws_size;
  const float* x = (const float*)d_in[0];
  const float* A = (const float*)d_in[1];
  const float* W = (const float*)d_in[2];
  const float* b = (const float*)d_in[3];
  float* out = (float*)d_out;
  u16* wb = (u16*)d_ws;                        // 128 KB only

  k0_wcast<<<64, 256, 0, stream>>>(W, wb);
  k_fused<<<dim3(59, 32), 512, 0, stream>>>(x, A, wb, b, out);
}